// Round 2
// baseline (9709.766 us; speedup 1.0000x reference)
//
#include <hip/hip_runtime.h>
#include <hip/hip_bf16.h>

// DTYPE THEORY (round 2): reference declares all arrays jnp.float32; harness
// instruction says float32 -> const float*. Round-1 NaN is fully explained by
// misreading f32 buffers as bf16 (mantissa-garbage low halves -> inf/NaN).
// => inputs f32, output f32, keep f32 precision end-to-end.

typedef __hip_bfloat16 bf16;

#define S_TOK   2048
#define NROWS   4096        // B*S
#define NH      16
#define QKD     192
#define NOPE_   128
#define ROPE_   64
#define VDIM_   128
#define RANK    512
#define SCALE_F 0.07216878364870323f   // 192^-0.5
#define NEG_BIG -3.0e38f

__device__ __forceinline__ float bl(unsigned u){ union{unsigned i; float f;} t; t.i = u << 16; return t.f; }
__device__ __forceinline__ float bh(unsigned u){ union{unsigned i; float f;} t; t.i = u & 0xffff0000u; return t.f; }
__device__ __forceinline__ unsigned short f2b(float f){
  bf16 h = __float2bfloat16(f);
  return *reinterpret_cast<unsigned short*>(&h);
}
__device__ __forceinline__ void store4(float* p, float a, float b, float c, float d){
  *(float4*)p = make_float4(a,b,c,d);
}
__device__ __forceinline__ void store4(bf16* p, float a, float b, float c, float d){
  ushort4 u; u.x=f2b(a); u.y=f2b(b); u.z=f2b(c); u.w=f2b(d);
  *(ushort4*)p = u;
}

// ---------------------------------------------------------------------------
// Tiled GEMM, f32 in / f32 accumulate / TOUT out.
// BN_MODE==0: C[M,N] = A[M,K] * W[N,K]^T ; BN_MODE==1: C[M,N] = A[M,K] * W[K,N]
// grid = (N/64, M/64, Z). K multiple of 32, M,N multiples of 64.
// ---------------------------------------------------------------------------
template<int BN_MODE, typename TOUT>
__global__ __launch_bounds__(256) void gemm_tiled(
    const float* __restrict__ A, const float* __restrict__ W, TOUT* __restrict__ C,
    int K, int lda, int ldw, int ldc, long azs, long wzs, long czs)
{
  A += (long)blockIdx.z * azs;
  W += (long)blockIdx.z * wzs;
  C += (long)blockIdx.z * czs;
  __shared__ __align__(16) float As[32 * 68];
  __shared__ __align__(16) float Ws[32 * 68];
  const int tid = threadIdx.x;
  const int m0 = blockIdx.y << 6, n0 = blockIdx.x << 6;
  const int tx = tid & 15, ty = tid >> 4;
  float acc[4][4] = {};

  const int am = tid >> 2;            // 0..63  row within tile
  const int ak = (tid & 3) << 3;      // 0,8,16,24
  const float* Ap = A + (long)(m0 + am) * lda + ak;
  const float* Wp;
  int wk = 0, wn = 0;
  if (BN_MODE) { wk = tid >> 3; wn = (tid & 7) << 3; Wp = W + (long)wk * ldw + n0 + wn; }
  else         { Wp = W + (long)(n0 + am) * ldw + ak; }

  for (int k0 = 0; k0 < K; k0 += 32) {
    float4 a0 = *(const float4*)(Ap + k0);
    float4 a1 = *(const float4*)(Ap + k0 + 4);
    float4 w0, w1;
    if (BN_MODE) { w0 = *(const float4*)(Wp + (long)k0 * ldw);
                   w1 = *(const float4*)(Wp + (long)k0 * ldw + 4); }
    else         { w0 = *(const float4*)(Wp + k0);
                   w1 = *(const float4*)(Wp + k0 + 4); }
    __syncthreads();   // previous iteration's LDS reads done
    As[(ak+0)*68+am]=a0.x; As[(ak+1)*68+am]=a0.y; As[(ak+2)*68+am]=a0.z; As[(ak+3)*68+am]=a0.w;
    As[(ak+4)*68+am]=a1.x; As[(ak+5)*68+am]=a1.y; As[(ak+6)*68+am]=a1.z; As[(ak+7)*68+am]=a1.w;
    if (BN_MODE) {
      *(float4*)(Ws + wk*68 + wn)     = w0;
      *(float4*)(Ws + wk*68 + wn + 4) = w1;
    } else {
      Ws[(ak+0)*68+am]=w0.x; Ws[(ak+1)*68+am]=w0.y; Ws[(ak+2)*68+am]=w0.z; Ws[(ak+3)*68+am]=w0.w;
      Ws[(ak+4)*68+am]=w1.x; Ws[(ak+5)*68+am]=w1.y; Ws[(ak+6)*68+am]=w1.z; Ws[(ak+7)*68+am]=w1.w;
    }
    __syncthreads();
    #pragma unroll
    for (int kk = 0; kk < 32; ++kk) {
      float4 a4 = *(const float4*)(As + kk*68 + (ty<<2));
      float4 b4 = *(const float4*)(Ws + kk*68 + (tx<<2));
      acc[0][0] += a4.x*b4.x; acc[0][1] += a4.x*b4.y; acc[0][2] += a4.x*b4.z; acc[0][3] += a4.x*b4.w;
      acc[1][0] += a4.y*b4.x; acc[1][1] += a4.y*b4.y; acc[1][2] += a4.y*b4.z; acc[1][3] += a4.y*b4.w;
      acc[2][0] += a4.z*b4.x; acc[2][1] += a4.z*b4.y; acc[2][2] += a4.z*b4.z; acc[2][3] += a4.z*b4.w;
      acc[3][0] += a4.w*b4.x; acc[3][1] += a4.w*b4.y; acc[3][2] += a4.w*b4.z; acc[3][3] += a4.w*b4.w;
    }
  }
  #pragma unroll
  for (int i = 0; i < 4; ++i)
    store4(C + (long)(m0 + (ty<<2) + i) * ldc + n0 + (tx<<2),
           acc[i][0], acc[i][1], acc[i][2], acc[i][3]);
}

// ---------------------------------------------------------------------------
// kvprep: per row — RMSNorm first 512 -> ckv (f32), RoPE last 64 -> kpe (f32)
// ---------------------------------------------------------------------------
__global__ __launch_bounds__(64) void kvprep(
    const float* __restrict__ kvbuf, const float* __restrict__ wnorm,
    const float* __restrict__ cosb, const float* __restrict__ sinb,
    float* __restrict__ ckv, float* __restrict__ kpe)
{
  const int row = blockIdx.x;
  const int s = row & (S_TOK - 1);
  const int lane = threadIdx.x;
  const float* kr = kvbuf + (long)row * 576;
  float4 v0 = *(const float4*)(kr + lane*8);
  float4 v1 = *(const float4*)(kr + lane*8 + 4);
  float ss = v0.x*v0.x + v0.y*v0.y + v0.z*v0.z + v0.w*v0.w
           + v1.x*v1.x + v1.y*v1.y + v1.z*v1.z + v1.w*v1.w;
  #pragma unroll
  for (int off = 32; off > 0; off >>= 1) ss += __shfl_down(ss, off);
  ss = __shfl(ss, 0);
  const float scl = rsqrtf(ss * (1.0f/512.0f) + 1e-6f);
  float4 w0 = *(const float4*)(wnorm + lane*8);
  float4 w1 = *(const float4*)(wnorm + lane*8 + 4);
  float* cd = ckv + (long)row*512 + lane*8;
  *(float4*)(cd)     = make_float4(v0.x*scl*w0.x, v0.y*scl*w0.y, v0.z*scl*w0.z, v0.w*scl*w0.w);
  *(float4*)(cd + 4) = make_float4(v1.x*scl*w1.x, v1.y*scl*w1.y, v1.z*scl*w1.z, v1.w*scl*w1.w);
  if (lane < 32) {
    float xe = kr[512 + 2*lane], xo = kr[512 + 2*lane + 1];
    float c = cosb[s*32 + lane], sn = sinb[s*32 + lane];
    kpe[(long)row*64 + 2*lane]     = xe*c - xo*sn;
    kpe[(long)row*64 + 2*lane + 1] = xe*sn + xo*c;
  }
}

// ---------------------------------------------------------------------------
// ropeq: in-place RoPE on q_pe slice of qbuf (rows x 3072, pe at h*192+128)
// ---------------------------------------------------------------------------
__global__ __launch_bounds__(256) void ropeq(
    float* __restrict__ qbuf, const float* __restrict__ cosb, const float* __restrict__ sinb)
{
  int gid = blockIdx.x * 256 + threadIdx.x;       // 4096*16*32 = 2,097,152
  int row = gid >> 9; int rem = gid & 511;
  int h = rem >> 5, i = rem & 31;
  int s = row & (S_TOK - 1);
  float* p = qbuf + (long)row*3072 + h*QKD + NOPE_ + 2*i;
  float xe = p[0], xo = p[1];
  float c = cosb[s*32 + i], sn = sinb[s*32 + i];
  p[0] = xe*c - xo*sn;
  p[1] = xe*sn + xo*c;
}

// ---------------------------------------------------------------------------
// Attention: one block per (b,s). All 16 heads share the c_kv K-tile (8 tokens).
// Online softmax (f32), fused o = o_lat @ wb_v^T epilogue. All-f32 precision.
// ---------------------------------------------------------------------------
#define CKV_ST 516   // 512 + 4 pad (f32): breaks 512-stride bank aliasing
#define PE_ST  68    // 64 + 4 pad

__device__ __forceinline__ void load_qlat(const float* q, float* qs, int tid, long row){
  const float4* g = (const float4*)(q + row * (long)(NH*RANK));
  #pragma unroll
  for (int j = 0; j < 8; ++j) {
    int f = tid + j*256; int hh = f >> 7, c4 = f & 127;
    *(float4*)(qs + hh*CKV_ST + (c4<<2)) = g[f];
  }
}
__device__ __forceinline__ void load_qlat(const bf16* q, float* qs, int tid, long row){
  const uint4* g = (const uint4*)(q + row * (long)(NH*RANK));
  #pragma unroll
  for (int j = 0; j < 4; ++j) {
    int f = tid + j*256; int hh = f >> 6, c8 = f & 63;
    uint4 v = g[f]; float* d = qs + hh*CKV_ST + (c8<<3);
    d[0]=bl(v.x); d[1]=bh(v.x); d[2]=bl(v.y); d[3]=bh(v.y);
    d[4]=bl(v.z); d[5]=bh(v.z); d[6]=bl(v.w); d[7]=bh(v.w);
  }
}

template<typename TQL>
__global__ __launch_bounds__(256) void attn_kernel(
    const TQL* __restrict__ qlat,    // (4096, 16*512)
    const float* __restrict__ qbuf,  // (4096, 3072) — pe slice (rope'd)
    const float* __restrict__ ckv,   // (4096, 512)
    const float* __restrict__ kpe,   // (4096, 64)
    const float* __restrict__ wkvb,  // (16,256,512)
    float* __restrict__ obuf)        // (4096, 2048)
{
  const int row = blockIdx.x;
  const int b = row >> 11;
  const int s = row & (S_TOK - 1);
  const int tid = threadIdx.x;

  __shared__ __align__(16) float qlat_s[NH * CKV_ST];   // 33,024 B (olat aliases at end)
  __shared__ __align__(16) float ckv_s[8 * CKV_ST];     // 16,512 B
  __shared__ __align__(16) float qpe_s[NH * PE_ST];     //  4,352 B
  __shared__ __align__(16) float kpe_s[8 * PE_ST];      //  2,176 B
  __shared__ float sc_s[NH * 8];                        //    512 B
  __shared__ float mrun[NH], lrun[NH], alpha_s[NH];

  load_qlat(qlat, qlat_s, tid, (long)row);
  { int hh = tid >> 4, r = (tid & 15) << 2;
    float4 v = *(const float4*)(qbuf + (long)row*3072 + hh*QKD + NOPE_ + r);
    *(float4*)(qpe_s + hh*PE_ST + r) = v; }
  if (tid < NH) { mrun[tid] = NEG_BIG; lrun[tid] = 0.f; }
  __syncthreads();

  const int h  = tid >> 4, l = tid & 15, cs = l << 5;
  const int pair = tid >> 1, half = tid & 1;
  const int sh = pair >> 3, st = pair & 7, coff = half << 8;
  float oacc[32] = {};

  const int ntile = (s >> 3) + 1;
  for (int tile = 0; tile < ntile; ++tile) {
    const int t0 = tile << 3;
    // ---- load K-tile: 8 x 512 ckv + 8 x 64 kpe ----
    {
      const float4* g = (const float4*)(ckv + (long)(b*S_TOK + t0) * 512);
      #pragma unroll
      for (int j = 0; j < 4; ++j) {
        int f = tid + j*256; int r = f >> 7, c4 = f & 127;
        *(float4*)(ckv_s + r*CKV_ST + (c4<<2)) = g[f];
      }
      if (tid < 128) {
        int r = tid >> 4, c4 = tid & 15;
        *(float4*)(kpe_s + r*PE_ST + (c4<<2)) =
            ((const float4*)(kpe + (long)(b*S_TOK + t0) * 64))[tid];
      }
    }
    __syncthreads();
    // ---- scores: 128 (h,t) pairs, 2 threads per pair (c-halves) ----
    {
      const float4* qv  = (const float4*)(qlat_s + sh*CKV_ST + coff);
      const float4* kv4 = (const float4*)(ckv_s  + st*CKV_ST + coff);
      float acc = 0.f;
      #pragma unroll 8
      for (int c = 0; c < 64; ++c) {
        float4 a = qv[c], k = kv4[c];
        acc += a.x*k.x + a.y*k.y + a.z*k.z + a.w*k.w;
      }
      const float4* qp = (const float4*)(qpe_s + sh*PE_ST + (half<<5));
      const float4* kp = (const float4*)(kpe_s + st*PE_ST + (half<<5));
      #pragma unroll
      for (int r = 0; r < 8; ++r) {
        float4 a = qp[r], k = kp[r];
        acc += a.x*k.x + a.y*k.y + a.z*k.z + a.w*k.w;
      }
      acc += __shfl_xor(acc, 1);
      if (half == 0)
        sc_s[sh*8 + st] = (t0 + st <= s) ? acc * SCALE_F : NEG_BIG;
    }
    __syncthreads();
    // ---- online softmax bookkeeping (one thread per head) ----
    if (tid < NH) {
      float m_old = mrun[tid], mn = m_old;
      #pragma unroll
      for (int tt = 0; tt < 8; ++tt) mn = fmaxf(mn, sc_s[tid*8 + tt]);
      float al = __expf(m_old - mn);
      float lsum = lrun[tid] * al;
      #pragma unroll
      for (int tt = 0; tt < 8; ++tt) {
        float ps = __expf(sc_s[tid*8 + tt] - mn);
        sc_s[tid*8 + tt] = ps; lsum += ps;
      }
      mrun[tid] = mn; lrun[tid] = lsum; alpha_s[tid] = al;
    }
    __syncthreads();
    // ---- rescale + accumulate o_lat (thread = (h, 32-wide c segment)) ----
    {
      float al = alpha_s[h];
      #pragma unroll
      for (int c = 0; c < 32; ++c) oacc[c] *= al;
      const float* scr = sc_s + h*8;
      #pragma unroll
      for (int i = 0; i < 8; ++i) {
        int tt = (i + l) & 7;              // rotate: 2-way max bank aliasing
        float p = scr[tt];
        const float4* kr = (const float4*)(ckv_s + tt*CKV_ST + cs);
        #pragma unroll
        for (int j = 0; j < 8; ++j) {
          float4 v = kr[j]; float* o = oacc + j*4;
          o[0] += p*v.x; o[1] += p*v.y; o[2] += p*v.z; o[3] += p*v.w;
        }
      }
    }
    __syncthreads();
  }

  // ---- epilogue: olat (aliases qlat_s), then o[h,d] = dot(olat[h,:], wb_v[h,d,:]) ----
  float* olat_s = qlat_s;
  {
    float linv = 1.0f / lrun[h];
    #pragma unroll
    for (int c = 0; c < 32; ++c) olat_s[h*RANK + cs + c] = oacc[c] * linv;
  }
  __syncthreads();
  {
    const int d0 = l << 3;               // 8 outputs per thread
    const float4* ol = (const float4*)(olat_s + h * RANK);
    const float* wv = wkvb + ((long)(h*256 + NOPE_ + d0)) * 512;
    float out8[8];
    #pragma unroll
    for (int d = 0; d < 8; ++d) {
      const float4* wr = (const float4*)(wv + (long)d * 512);
      float acc = 0.f;
      #pragma unroll 8
      for (int c = 0; c < 128; ++c) {
        float4 w = wr[c], o = ol[c];
        acc += o.x*w.x + o.y*w.y + o.z*w.z + o.w*w.w;
      }
      out8[d] = acc;
    }
    float* op = obuf + (long)row*2048 + h*VDIM_ + d0;
    *(float4*)(op)     = make_float4(out8[0], out8[1], out8[2], out8[3]);
    *(float4*)(op + 4) = make_float4(out8[4], out8[5], out8[6], out8[7]);
  }
}

// ---------------------------------------------------------------------------
extern "C" void kernel_launch(void* const* d_in, const int* in_sizes, int n_in,
                              void* d_out, int out_size, void* d_ws, size_t ws_size,
                              hipStream_t stream)
{
  const float* x     = (const float*)d_in[0];
  const float* wq    = (const float*)d_in[1];
  const float* wkv_a = (const float*)d_in[2];
  const float* kvnw  = (const float*)d_in[3];
  const float* wkv_b = (const float*)d_in[4];
  const float* wo    = (const float*)d_in[5];
  const float* cosb  = (const float*)d_in[6];
  const float* sinb  = (const float*)d_in[7];
  float* out = (float*)d_out;

  size_t off = 0;
  char* wsb = (char*)d_ws;
  float* qbuf  = (float*)(wsb + off); off += (size_t)NROWS * 3072 * 4;   // 50.3 MB
  float* kvbuf = (float*)(wsb + off); off += (size_t)NROWS * 576  * 4;   //  9.4 MB
  float* ckvb  = (float*)(wsb + off); off += (size_t)NROWS * 512  * 4;   //  8.4 MB
  float* kpeb  = (float*)(wsb + off); off += (size_t)NROWS * 64   * 4;   //  1.0 MB
  // qlat tier: f32 (134 MB) if ws allows, else bf16 (67 MB)
  size_t need_f32 = off + (size_t)NROWS*8192*4 + (size_t)NROWS*2048*4;
  bool big = ws_size >= need_f32;
  float* qlatF = nullptr; bf16* qlatH = nullptr;
  if (big) { qlatF = (float*)(wsb + off); off += (size_t)NROWS * 8192 * 4; }
  else     { qlatH = (bf16*) (wsb + off); off += (size_t)NROWS * 8192 * 2; }
  float* obuf  = (float*)(wsb + off); off += (size_t)NROWS * 2048 * 4;   // 33.5 MB

  dim3 blk(256);
  // q = x @ wq^T  -> (4096, 3072)
  gemm_tiled<0,float><<<dim3(3072/64, NROWS/64, 1), blk, 0, stream>>>(
      x, wq, qbuf, 2048, 2048, 2048, 3072, 0, 0, 0);
  // rope q_pe in place
  ropeq<<<dim3(8192), blk, 0, stream>>>(qbuf, cosb, sinb);
  // kv = x @ wkv_a^T -> (4096, 576)
  gemm_tiled<0,float><<<dim3(576/64, NROWS/64, 1), blk, 0, stream>>>(
      x, wkv_a, kvbuf, 2048, 2048, 2048, 576, 0, 0, 0);
  // rmsnorm + rope k_pe
  kvprep<<<dim3(NROWS), dim3(64), 0, stream>>>(kvbuf, kvnw, cosb, sinb, ckvb, kpeb);
  // q_lat[h] = q_nope[:, h] @ wb_k[h]  (z = head)
  if (big) {
    gemm_tiled<1,float><<<dim3(512/64, NROWS/64, NH), blk, 0, stream>>>(
        qbuf, wkv_b, qlatF, 128, 3072, 512, 8192, (long)QKD, (long)256*512, (long)512);
    attn_kernel<float><<<dim3(NROWS), blk, 0, stream>>>(qlatF, qbuf, ckvb, kpeb, wkv_b, obuf);
  } else {
    gemm_tiled<1,bf16><<<dim3(512/64, NROWS/64, NH), blk, 0, stream>>>(
        qbuf, wkv_b, qlatH, 128, 3072, 512, 8192, (long)QKD, (long)256*512, (long)512);
    attn_kernel<bf16><<<dim3(NROWS), blk, 0, stream>>>(qlatH, qbuf, ckvb, kpeb, wkv_b, obuf);
  }
  // out = o @ wo^T
  gemm_tiled<0,float><<<dim3(2048/64, NROWS/64, 1), blk, 0, stream>>>(
      obuf, wo, out, 2048, 2048, 2048, 2048, 0, 0, 0);
}

// Round 3
// 3734.121 us; speedup vs baseline: 2.6003x; 2.6003x over previous
//
#include <hip/hip_runtime.h>
#include <hip/hip_bf16.h>

typedef __hip_bfloat16 bf16;
typedef __attribute__((ext_vector_type(8))) short short8;   // 8 bf16 = 4 VGPRs (MFMA A/B frag)
typedef __attribute__((ext_vector_type(4))) float f32x4;    // MFMA C/D frag

#define S_TOK   2048
#define NROWS   4096        // B*S
#define NH      16
#define QKD     192
#define NOPE_   128
#define ROPE_   64
#define VDIM_   128
#define RANK    512
#define SCALE_F 0.07216878364870323f   // 192^-0.5
#define NEG_BIG -3.0e38f

__device__ __forceinline__ unsigned short f2b(float f){
  bf16 h = __float2bfloat16(f);
  return *reinterpret_cast<unsigned short*>(&h);
}
__device__ __forceinline__ void store4(float* p, float a, float b, float c, float d){
  *(float4*)p = make_float4(a,b,c,d);
}
__device__ __forceinline__ void store4(bf16* p, float a, float b, float c, float d){
  ushort4 u; u.x=f2b(a); u.y=f2b(b); u.z=f2b(c); u.w=f2b(d);
  *(ushort4*)p = u;
}
union U8 { uint4 u; short8 s; };
#define MFMA16x32(a,b,c) __builtin_amdgcn_mfma_f32_16x16x32_bf16(a,b,c,0,0,0)

// ---------------------------------------------------------------------------
// Tiled f32 GEMM (unchanged from round 2, correctness-proven).
// BN_MODE==0: C = A[M,K] * W[N,K]^T ; BN_MODE==1: C = A[M,K] * W[K,N]
// ---------------------------------------------------------------------------
template<int BN_MODE, typename TOUT>
__global__ __launch_bounds__(256) void gemm_tiled(
    const float* __restrict__ A, const float* __restrict__ W, TOUT* __restrict__ C,
    int K, int lda, int ldw, int ldc, long azs, long wzs, long czs)
{
  A += (long)blockIdx.z * azs;
  W += (long)blockIdx.z * wzs;
  C += (long)blockIdx.z * czs;
  __shared__ __align__(16) float As[32 * 68];
  __shared__ __align__(16) float Ws[32 * 68];
  const int tid = threadIdx.x;
  const int m0 = blockIdx.y << 6, n0 = blockIdx.x << 6;
  const int tx = tid & 15, ty = tid >> 4;
  float acc[4][4] = {};

  const int am = tid >> 2;
  const int ak = (tid & 3) << 3;
  const float* Ap = A + (long)(m0 + am) * lda + ak;
  const float* Wp;
  int wk = 0, wn = 0;
  if (BN_MODE) { wk = tid >> 3; wn = (tid & 7) << 3; Wp = W + (long)wk * ldw + n0 + wn; }
  else         { Wp = W + (long)(n0 + am) * ldw + ak; }

  for (int k0 = 0; k0 < K; k0 += 32) {
    float4 a0 = *(const float4*)(Ap + k0);
    float4 a1 = *(const float4*)(Ap + k0 + 4);
    float4 w0, w1;
    if (BN_MODE) { w0 = *(const float4*)(Wp + (long)k0 * ldw);
                   w1 = *(const float4*)(Wp + (long)k0 * ldw + 4); }
    else         { w0 = *(const float4*)(Wp + k0);
                   w1 = *(const float4*)(Wp + k0 + 4); }
    __syncthreads();
    As[(ak+0)*68+am]=a0.x; As[(ak+1)*68+am]=a0.y; As[(ak+2)*68+am]=a0.z; As[(ak+3)*68+am]=a0.w;
    As[(ak+4)*68+am]=a1.x; As[(ak+5)*68+am]=a1.y; As[(ak+6)*68+am]=a1.z; As[(ak+7)*68+am]=a1.w;
    if (BN_MODE) {
      *(float4*)(Ws + wk*68 + wn)     = w0;
      *(float4*)(Ws + wk*68 + wn + 4) = w1;
    } else {
      Ws[(ak+0)*68+am]=w0.x; Ws[(ak+1)*68+am]=w0.y; Ws[(ak+2)*68+am]=w0.z; Ws[(ak+3)*68+am]=w0.w;
      Ws[(ak+4)*68+am]=w1.x; Ws[(ak+5)*68+am]=w1.y; Ws[(ak+6)*68+am]=w1.z; Ws[(ak+7)*68+am]=w1.w;
    }
    __syncthreads();
    #pragma unroll
    for (int kk = 0; kk < 32; ++kk) {
      float4 a4 = *(const float4*)(As + kk*68 + (ty<<2));
      float4 b4 = *(const float4*)(Ws + kk*68 + (tx<<2));
      acc[0][0] += a4.x*b4.x; acc[0][1] += a4.x*b4.y; acc[0][2] += a4.x*b4.z; acc[0][3] += a4.x*b4.w;
      acc[1][0] += a4.y*b4.x; acc[1][1] += a4.y*b4.y; acc[1][2] += a4.y*b4.z; acc[1][3] += a4.y*b4.w;
      acc[2][0] += a4.z*b4.x; acc[2][1] += a4.z*b4.y; acc[2][2] += a4.z*b4.z; acc[2][3] += a4.z*b4.w;
      acc[3][0] += a4.w*b4.x; acc[3][1] += a4.w*b4.y; acc[3][2] += a4.w*b4.z; acc[3][3] += a4.w*b4.w;
    }
  }
  #pragma unroll
  for (int i = 0; i < 4; ++i)
    store4(C + (long)(m0 + (ty<<2) + i) * ldc + n0 + (tx<<2),
           acc[i][0], acc[i][1], acc[i][2], acc[i][3]);
}

// ---------------------------------------------------------------------------
// kvprep: RMSNorm first 512 -> ckv (bf16), RoPE last 64 -> kpe (bf16)
// ---------------------------------------------------------------------------
__global__ __launch_bounds__(64) void kvprep(
    const float* __restrict__ kvbuf, const float* __restrict__ wnorm,
    const float* __restrict__ cosb, const float* __restrict__ sinb,
    bf16* __restrict__ ckv, bf16* __restrict__ kpe)
{
  const int row = blockIdx.x;
  const int s = row & (S_TOK - 1);
  const int lane = threadIdx.x;
  const float* kr = kvbuf + (long)row * 576;
  float4 v0 = *(const float4*)(kr + lane*8);
  float4 v1 = *(const float4*)(kr + lane*8 + 4);
  float ss = v0.x*v0.x + v0.y*v0.y + v0.z*v0.z + v0.w*v0.w
           + v1.x*v1.x + v1.y*v1.y + v1.z*v1.z + v1.w*v1.w;
  #pragma unroll
  for (int off = 32; off > 0; off >>= 1) ss += __shfl_down(ss, off);
  ss = __shfl(ss, 0);
  const float scl = rsqrtf(ss * (1.0f/512.0f) + 1e-6f);
  float4 w0 = *(const float4*)(wnorm + lane*8);
  float4 w1 = *(const float4*)(wnorm + lane*8 + 4);
  bf16* cd = ckv + (long)row*512 + lane*8;
  store4(cd,   v0.x*scl*w0.x, v0.y*scl*w0.y, v0.z*scl*w0.z, v0.w*scl*w0.w);
  store4(cd+4, v1.x*scl*w1.x, v1.y*scl*w1.y, v1.z*scl*w1.z, v1.w*scl*w1.w);
  if (lane < 32) {
    float xe = kr[512 + 2*lane], xo = kr[512 + 2*lane + 1];
    float c = cosb[s*32 + lane], sn = sinb[s*32 + lane];
    unsigned short* kp = (unsigned short*)kpe + (long)row*64 + 2*lane;
    ushort2 u; u.x = f2b(xe*c - xo*sn); u.y = f2b(xe*sn + xo*c);
    *(ushort2*)kp = u;
  }
}

// ---------------------------------------------------------------------------
// ropeq: RoPE q_pe slice of qbuf (f32) -> qpe (bf16, 4096 x 16*64)
// ---------------------------------------------------------------------------
__global__ __launch_bounds__(256) void ropeq(
    const float* __restrict__ qbuf, const float* __restrict__ cosb,
    const float* __restrict__ sinb, bf16* __restrict__ qpe)
{
  int gid = blockIdx.x * 256 + threadIdx.x;       // 4096*16*32
  int row = gid >> 9; int rem = gid & 511;
  int h = rem >> 5, i = rem & 31;
  int s = row & (S_TOK - 1);
  const float* p = qbuf + (long)row*3072 + h*QKD + NOPE_ + 2*i;
  float xe = p[0], xo = p[1];
  float c = cosb[s*32 + i], sn = sinb[s*32 + i];
  unsigned short* o = (unsigned short*)qpe + (long)row*1024 + h*64 + 2*i;
  ushort2 u; u.x = f2b(xe*c - xo*sn); u.y = f2b(xe*sn + xo*c);
  *(ushort2*)o = u;
}

// ---------------------------------------------------------------------------
// tr64: ckv (b, t, c) -> ckvT (b, c, t), bf16, 64x64 LDS tiles
// grid (S/64, 512/64, B)
// ---------------------------------------------------------------------------
__global__ __launch_bounds__(256) void tr64(const bf16* __restrict__ ckv,
                                            bf16* __restrict__ ckvT)
{
  const int t0 = blockIdx.x << 6, c0 = blockIdx.y << 6, b = blockIdx.z;
  const int tid = threadIdx.x;
  __shared__ unsigned short tile[64*65];
  const unsigned short* src = (const unsigned short*)ckv + (long)b*S_TOK*512;
  #pragma unroll
  for (int j = 0; j < 16; ++j) {
    int idx = tid + j*256; int r = idx >> 6, c = idx & 63;
    tile[r*65 + c] = src[(long)(t0+r)*512 + c0 + c];
  }
  __syncthreads();
  unsigned short* dst = (unsigned short*)ckvT + (long)b*512*S_TOK;
  #pragma unroll
  for (int j = 0; j < 16; ++j) {
    int idx = tid + j*256; int r = idx >> 6, t = idx & 63;
    dst[(long)(c0+r)*S_TOK + t0 + t] = tile[t*65 + r];
  }
}

// ---------------------------------------------------------------------------
// wbv_cvt: wkv_b V-half (16 x 128 x 512 f32) -> bf16
// ---------------------------------------------------------------------------
__global__ __launch_bounds__(256) void wbv_cvt(const float* __restrict__ wkvb,
                                               bf16* __restrict__ wbv)
{
  int g = blockIdx.x * 256 + threadIdx.x;       // 1,048,576
  int h = g >> 16, rem = g & 65535;
  ((unsigned short*)wbv)[g] = f2b(wkvb[((long)(h*256 + NOPE_))*512 + rem]);
}

// ---------------------------------------------------------------------------
// MFMA flash attention.
// Block = (b, h, 64-query tile). 4 waves x 16 query rows. 32-token K-tiles.
// QK^T: Q frags in regs (A), K staged natural in LDS (B, contiguous b128).
// P: LDS roundtrip (C-layout -> A-layout). PV: B frags direct from global ckvT.
// Epilogue: o = o_lat @ wb_v^T fused (MFMA), o_lat via LDS overlay, 2 passes.
// ---------------------------------------------------------------------------
#define KVST 584   // 32-row LDS stride in halves (16B aligned; 2-way max = free)

__global__ __launch_bounds__(256, 2) void attn_mfma(
    const bf16* __restrict__ qlat,   // (4096, 16*512)
    const bf16* __restrict__ qpe,    // (4096, 16*64)
    const bf16* __restrict__ ckv,    // (4096, 512)
    const bf16* __restrict__ kpe,    // (4096, 64)
    const bf16* __restrict__ ckvT,   // (B, 512, 2048)
    const bf16* __restrict__ wbv,    // (16, 128, 512)
    float* __restrict__ obuf)        // (4096, 2048)
{
  const int idx = blockIdx.x;
  const int qt = 31 - (idx & 31);            // big q-tiles dispatch first
  const int h  = (idx >> 5) & 15;
  const int b  = idx >> 9;
  const int q0 = qt << 6;
  const int tid = threadIdx.x;
  const int w = tid >> 6, lane = tid & 63;
  const int quad = lane >> 4, l16 = lane & 15;

  __shared__ __align__(16) unsigned short kv_s[32 * KVST];   // 37376 B
  __shared__ __align__(16) unsigned short P_s[4 * 16 * 40];  //  5120 B

  // ---- Q fragments: A[m=l16][k=quad*8+j], 18 chunks of K=32 (512 lat + 64 pe)
  const long qrow = (long)b*S_TOK + q0 + w*16 + l16;
  short8 qf[18];
  {
    const unsigned short* qlp = (const unsigned short*)qlat + qrow*8192 + h*512 + quad*8;
    const unsigned short* qpp = (const unsigned short*)qpe  + qrow*1024 + h*64  + quad*8;
    #pragma unroll
    for (int kc = 0; kc < 16; ++kc) { U8 t; t.u = *(const uint4*)(qlp + kc*32); qf[kc] = t.s; }
    { U8 t; t.u = *(const uint4*)(qpp);      qf[16] = t.s; }
    { U8 t; t.u = *(const uint4*)(qpp + 32); qf[17] = t.s; }
  }

  f32x4 acc[32];
  #pragma unroll
  for (int i = 0; i < 32; ++i) acc[i] = (f32x4){0.f,0.f,0.f,0.f};
  float mi[4] = {NEG_BIG,NEG_BIG,NEG_BIG,NEG_BIG};
  float li[4] = {0.f,0.f,0.f,0.f};

  const int myqmax = q0 + w*16 + 15;
  const int ntiles = (q0 >> 5) + 2;          // (q0+64)/32
  const unsigned short* ckv_b  = (const unsigned short*)ckv  + (long)b*S_TOK*512;
  const unsigned short* kpe_b  = (const unsigned short*)kpe  + (long)b*S_TOK*64;
  const unsigned short* ckvT_b = (const unsigned short*)ckvT + (long)b*512*S_TOK;
  unsigned short* Pw = P_s + w*640;

  for (int tile = 0; tile < ntiles; ++tile) {
    const int t0 = tile << 5;
    // ---- stage K-tile (32 x 576 bf16) into kv_s ----
    #pragma unroll
    for (int j = 0; j < 8; ++j) {
      int f = tid + j*256;                   // 2048 uint4 slots (32x512)
      int r = f >> 6, c8 = f & 63;
      *(uint4*)(kv_s + r*KVST + c8*8) = *(const uint4*)(ckv_b + (long)(t0+r)*512 + c8*8);
    }
    { int r = tid >> 3, c8 = tid & 7;        // 32x64 pe -> cols 512..575
      *(uint4*)(kv_s + r*KVST + 512 + c8*8) = *(const uint4*)(kpe_b + (long)(t0+r)*64 + c8*8); }
    __syncthreads();

    const bool active = (t0 <= myqmax);
    if (active) {
      // ---- scores: two 16x16 C-tiles (token halves) ----
      f32x4 sc0 = (f32x4){0.f,0.f,0.f,0.f}, sc1 = sc0;
      #pragma unroll
      for (int kc = 0; kc < 18; ++kc) {
        U8 b0; b0.u = *(const uint4*)(kv_s + l16*KVST      + kc*32 + quad*8);
        U8 b1; b1.u = *(const uint4*)(kv_s + (16+l16)*KVST + kc*32 + quad*8);
        sc0 = MFMA16x32(qf[kc], b0.s, sc0);
        sc1 = MFMA16x32(qf[kc], b1.s, sc1);
      }
      // ---- online softmax (C rows = quad*4+i, cols = l16 / 16+l16) ----
      float s0[4], s1[4], mx[4];
      #pragma unroll
      for (int i = 0; i < 4; ++i) {
        int qg = q0 + w*16 + quad*4 + i;
        s0[i] = (t0 + l16      <= qg) ? sc0[i]*SCALE_F : NEG_BIG;
        s1[i] = (t0 + 16 + l16 <= qg) ? sc1[i]*SCALE_F : NEG_BIG;
        mx[i] = fmaxf(mi[i], fmaxf(s0[i], s1[i]));
      }
      #pragma unroll
      for (int d = 1; d < 16; d <<= 1) {
        #pragma unroll
        for (int i = 0; i < 4; ++i) mx[i] = fmaxf(mx[i], __shfl_xor(mx[i], d));
      }
      float al[4], rs[4];
      #pragma unroll
      for (int i = 0; i < 4; ++i) {
        al[i] = __expf(mi[i] - mx[i]); mi[i] = mx[i];
        float p0 = __expf(s0[i] - mx[i]);
        float p1 = __expf(s1[i] - mx[i]);
        rs[i] = p0 + p1;
        Pw[(quad*4+i)*40 + l16]      = f2b(p0);
        Pw[(quad*4+i)*40 + 16 + l16] = f2b(p1);
      }
      #pragma unroll
      for (int d = 1; d < 16; d <<= 1) {
        #pragma unroll
        for (int i = 0; i < 4; ++i) rs[i] += __shfl_xor(rs[i], d);
      }
      #pragma unroll
      for (int i = 0; i < 4; ++i) li[i] = li[i]*al[i] + rs[i];
      #pragma unroll
      for (int nt = 0; nt < 32; ++nt) {
        #pragma unroll
        for (int i = 0; i < 4; ++i) acc[nt][i] *= al[i];
      }
      // ---- PV: A = P (LDS roundtrip), B = V from global ckvT ----
      U8 ap; ap.u = *(const uint4*)(Pw + l16*40 + quad*8);
      #pragma unroll
      for (int nt = 0; nt < 32; ++nt) {
        U8 bv; bv.u = *(const uint4*)(ckvT_b + (long)(nt*16 + l16)*S_TOK + t0 + quad*8);
        acc[nt] = MFMA16x32(ap.s, bv.s, acc[nt]);
      }
    }
    __syncthreads();   // kv_s reads done before next stage
  }

  // ---- epilogue: normalize, o_lat -> LDS (A layout), o = o_lat @ wb_v^T ----
  float linv[4];
  #pragma unroll
  for (int i = 0; i < 4; ++i) linv[i] = 1.0f / li[i];
  const int pass = w >> 1;
  unsigned short* ola = kv_s + (w & 1) * 16 * 520;
  #pragma unroll 1
  for (int p = 0; p < 2; ++p) {
    if (pass == p) {
      #pragma unroll
      for (int nt = 0; nt < 32; ++nt) {
        #pragma unroll
        for (int i = 0; i < 4; ++i)
          ola[(quad*4+i)*520 + nt*16 + l16] = f2b(acc[nt][i] * linv[i]);
      }
    }
    __syncthreads();
    if (pass == p) {
      f32x4 oc[8];
      #pragma unroll
      for (int nt = 0; nt < 8; ++nt) oc[nt] = (f32x4){0.f,0.f,0.f,0.f};
      #pragma unroll
      for (int kc = 0; kc < 16; ++kc) {
        U8 a; a.u = *(const uint4*)(ola + l16*520 + kc*32 + quad*8);
        #pragma unroll
        for (int nt = 0; nt < 8; ++nt) {
          U8 bw; bw.u = *(const uint4*)((const unsigned short*)wbv +
                         (long)(h*128 + nt*16 + l16)*512 + kc*32 + quad*8);
          oc[nt] = MFMA16x32(a.s, bw.s, oc[nt]);
        }
      }
      #pragma unroll
      for (int nt = 0; nt < 8; ++nt) {
        #pragma unroll
        for (int i = 0; i < 4; ++i)
          obuf[((long)b*S_TOK + q0 + w*16 + quad*4 + i)*2048 + h*128 + nt*16 + l16] = oc[nt][i];
      }
    }
    __syncthreads();
  }
}

// ---------------------------------------------------------------------------
extern "C" void kernel_launch(void* const* d_in, const int* in_sizes, int n_in,
                              void* d_out, int out_size, void* d_ws, size_t ws_size,
                              hipStream_t stream)
{
  const float* x     = (const float*)d_in[0];
  const float* wq    = (const float*)d_in[1];
  const float* wkv_a = (const float*)d_in[2];
  const float* kvnw  = (const float*)d_in[3];
  const float* wkv_b = (const float*)d_in[4];
  const float* wo    = (const float*)d_in[5];
  const float* cosb  = (const float*)d_in[6];
  const float* sinb  = (const float*)d_in[7];
  float* out = (float*)d_out;

  size_t off = 0;
  char* wsb = (char*)d_ws;
  float* qbuf  = (float*)(wsb + off); off += (size_t)NROWS * 3072 * 4;   // 50.3 MB
  float* kvbuf = (float*)(wsb + off); off += (size_t)NROWS * 576  * 4;   //  9.4 MB
  bf16*  ckvb  = (bf16*) (wsb + off); off += (size_t)NROWS * 512  * 2;   //  4.2 MB
  bf16*  kpeb  = (bf16*) (wsb + off); off += (size_t)NROWS * 64   * 2;   //  0.5 MB
  bf16*  qpeb  = (bf16*) (wsb + off); off += (size_t)NROWS * 1024 * 2;   //  8.4 MB
  bf16*  qlatb = (bf16*) (wsb + off); off += (size_t)NROWS * 8192 * 2;   // 67.1 MB
  bf16*  ckvT  = (bf16*) (wsb + off); off += (size_t)NROWS * 512  * 2;   //  4.2 MB
  bf16*  wbvb  = (bf16*) (wsb + off); off += (size_t)1048576 * 2;        //  2.1 MB
  float* obuf  = (float*)(wsb + off); off += (size_t)NROWS * 2048 * 4;   // 33.6 MB

  dim3 blk(256);
  // q = x @ wq^T (f32)
  gemm_tiled<0,float><<<dim3(3072/64, NROWS/64, 1), blk, 0, stream>>>(
      x, wq, qbuf, 2048, 2048, 2048, 3072, 0, 0, 0);
  // q_pe rope -> bf16
  ropeq<<<dim3(8192), blk, 0, stream>>>(qbuf, cosb, sinb, qpeb);
  // kv = x @ wkv_a^T (f32)
  gemm_tiled<0,float><<<dim3(576/64, NROWS/64, 1), blk, 0, stream>>>(
      x, wkv_a, kvbuf, 2048, 2048, 2048, 576, 0, 0, 0);
  // rmsnorm + rope k_pe -> bf16
  kvprep<<<dim3(NROWS), dim3(64), 0, stream>>>(kvbuf, kvnw, cosb, sinb, ckvb, kpeb);
  // ckv transpose for PV B-frags
  tr64<<<dim3(S_TOK/64, 512/64, 2), blk, 0, stream>>>(ckvb, ckvT);
  // q_lat[h] = q_nope @ wb_k[h]  -> bf16
  gemm_tiled<1,bf16><<<dim3(512/64, NROWS/64, NH), blk, 0, stream>>>(
      qbuf, wkv_b, qlatb, 128, 3072, 512, 8192, (long)QKD, (long)256*512, (long)512);
  // wb_v -> bf16
  wbv_cvt<<<dim3(4096), blk, 0, stream>>>(wkv_b, wbvb);
  // MFMA flash attention (+ fused o_lat @ wb_v^T)
  attn_mfma<<<dim3(1024), blk, 0, stream>>>(qlatb, qpeb, ckvb, kpeb, ckvT, wbvb, obuf);
  // out = o @ wo^T (f32)
  gemm_tiled<0,float><<<dim3(2048/64, NROWS/64, 1), blk, 0, stream>>>(
      obuf, wo, out, 2048, 2048, 2048, 2048, 0, 0, 0);
}

// Round 4
// 3102.271 us; speedup vs baseline: 3.1299x; 1.2037x over previous
//
#include <hip/hip_runtime.h>
#include <hip/hip_bf16.h>

typedef __hip_bfloat16 bf16;
typedef __attribute__((ext_vector_type(8))) short short8;   // 8 bf16 = 4 VGPRs (MFMA A/B frag)
typedef __attribute__((ext_vector_type(4))) float f32x4;    // MFMA C/D frag

#define S_TOK   2048
#define NROWS   4096        // B*S
#define NH      16
#define QKD     192
#define NOPE_   128
#define ROPE_   64
#define VDIM_   128
#define RANK    512
#define SCALE_F 0.07216878364870323f   // 192^-0.5
#define NEG_BIG -3.0e38f

__device__ __forceinline__ unsigned short f2b(float f){
  bf16 h = __float2bfloat16(f);
  return *reinterpret_cast<unsigned short*>(&h);
}
__device__ __forceinline__ void store4(float* p, float a, float b, float c, float d){
  *(float4*)p = make_float4(a,b,c,d);
}
__device__ __forceinline__ void store4(bf16* p, float a, float b, float c, float d){
  ushort4 u; u.x=f2b(a); u.y=f2b(b); u.z=f2b(c); u.w=f2b(d);
  *(ushort4*)p = u;
}
union U8 { uint4 u; short8 s; };
#define MFMA16x32(a,b,c) __builtin_amdgcn_mfma_f32_16x16x32_bf16(a,b,c,0,0,0)

// ---------------------------------------------------------------------------
// Tiled f32 GEMM (unchanged, correctness-proven).
// ---------------------------------------------------------------------------
template<int BN_MODE, typename TOUT>
__global__ __launch_bounds__(256) void gemm_tiled(
    const float* __restrict__ A, const float* __restrict__ W, TOUT* __restrict__ C,
    int K, int lda, int ldw, int ldc, long azs, long wzs, long czs)
{
  A += (long)blockIdx.z * azs;
  W += (long)blockIdx.z * wzs;
  C += (long)blockIdx.z * czs;
  __shared__ __align__(16) float As[32 * 68];
  __shared__ __align__(16) float Ws[32 * 68];
  const int tid = threadIdx.x;
  const int m0 = blockIdx.y << 6, n0 = blockIdx.x << 6;
  const int tx = tid & 15, ty = tid >> 4;
  float acc[4][4] = {};

  const int am = tid >> 2;
  const int ak = (tid & 3) << 3;
  const float* Ap = A + (long)(m0 + am) * lda + ak;
  const float* Wp;
  int wk = 0, wn = 0;
  if (BN_MODE) { wk = tid >> 3; wn = (tid & 7) << 3; Wp = W + (long)wk * ldw + n0 + wn; }
  else         { Wp = W + (long)(n0 + am) * ldw + ak; }

  for (int k0 = 0; k0 < K; k0 += 32) {
    float4 a0 = *(const float4*)(Ap + k0);
    float4 a1 = *(const float4*)(Ap + k0 + 4);
    float4 w0, w1;
    if (BN_MODE) { w0 = *(const float4*)(Wp + (long)k0 * ldw);
                   w1 = *(const float4*)(Wp + (long)k0 * ldw + 4); }
    else         { w0 = *(const float4*)(Wp + k0);
                   w1 = *(const float4*)(Wp + k0 + 4); }
    __syncthreads();
    As[(ak+0)*68+am]=a0.x; As[(ak+1)*68+am]=a0.y; As[(ak+2)*68+am]=a0.z; As[(ak+3)*68+am]=a0.w;
    As[(ak+4)*68+am]=a1.x; As[(ak+5)*68+am]=a1.y; As[(ak+6)*68+am]=a1.z; As[(ak+7)*68+am]=a1.w;
    if (BN_MODE) {
      *(float4*)(Ws + wk*68 + wn)     = w0;
      *(float4*)(Ws + wk*68 + wn + 4) = w1;
    } else {
      Ws[(ak+0)*68+am]=w0.x; Ws[(ak+1)*68+am]=w0.y; Ws[(ak+2)*68+am]=w0.z; Ws[(ak+3)*68+am]=w0.w;
      Ws[(ak+4)*68+am]=w1.x; Ws[(ak+5)*68+am]=w1.y; Ws[(ak+6)*68+am]=w1.z; Ws[(ak+7)*68+am]=w1.w;
    }
    __syncthreads();
    #pragma unroll
    for (int kk = 0; kk < 32; ++kk) {
      float4 a4 = *(const float4*)(As + kk*68 + (ty<<2));
      float4 b4 = *(const float4*)(Ws + kk*68 + (tx<<2));
      acc[0][0] += a4.x*b4.x; acc[0][1] += a4.x*b4.y; acc[0][2] += a4.x*b4.z; acc[0][3] += a4.x*b4.w;
      acc[1][0] += a4.y*b4.x; acc[1][1] += a4.y*b4.y; acc[1][2] += a4.y*b4.z; acc[1][3] += a4.y*b4.w;
      acc[2][0] += a4.z*b4.x; acc[2][1] += a4.z*b4.y; acc[2][2] += a4.z*b4.z; acc[2][3] += a4.z*b4.w;
      acc[3][0] += a4.w*b4.x; acc[3][1] += a4.w*b4.y; acc[3][2] += a4.w*b4.z; acc[3][3] += a4.w*b4.w;
    }
  }
  #pragma unroll
  for (int i = 0; i < 4; ++i)
    store4(C + (long)(m0 + (ty<<2) + i) * ldc + n0 + (tx<<2),
           acc[i][0], acc[i][1], acc[i][2], acc[i][3]);
}

// ---------------------------------------------------------------------------
__global__ __launch_bounds__(64) void kvprep(
    const float* __restrict__ kvbuf, const float* __restrict__ wnorm,
    const float* __restrict__ cosb, const float* __restrict__ sinb,
    bf16* __restrict__ ckv, bf16* __restrict__ kpe)
{
  const int row = blockIdx.x;
  const int s = row & (S_TOK - 1);
  const int lane = threadIdx.x;
  const float* kr = kvbuf + (long)row * 576;
  float4 v0 = *(const float4*)(kr + lane*8);
  float4 v1 = *(const float4*)(kr + lane*8 + 4);
  float ss = v0.x*v0.x + v0.y*v0.y + v0.z*v0.z + v0.w*v0.w
           + v1.x*v1.x + v1.y*v1.y + v1.z*v1.z + v1.w*v1.w;
  #pragma unroll
  for (int off = 32; off > 0; off >>= 1) ss += __shfl_down(ss, off);
  ss = __shfl(ss, 0);
  const float scl = rsqrtf(ss * (1.0f/512.0f) + 1e-6f);
  float4 w0 = *(const float4*)(wnorm + lane*8);
  float4 w1 = *(const float4*)(wnorm + lane*8 + 4);
  bf16* cd = ckv + (long)row*512 + lane*8;
  store4(cd,   v0.x*scl*w0.x, v0.y*scl*w0.y, v0.z*scl*w0.z, v0.w*scl*w0.w);
  store4(cd+4, v1.x*scl*w1.x, v1.y*scl*w1.y, v1.z*scl*w1.z, v1.w*scl*w1.w);
  if (lane < 32) {
    float xe = kr[512 + 2*lane], xo = kr[512 + 2*lane + 1];
    float c = cosb[s*32 + lane], sn = sinb[s*32 + lane];
    unsigned short* kp = (unsigned short*)kpe + (long)row*64 + 2*lane;
    ushort2 u; u.x = f2b(xe*c - xo*sn); u.y = f2b(xe*sn + xo*c);
    *(ushort2*)kp = u;
  }
}

// ---------------------------------------------------------------------------
__global__ __launch_bounds__(256) void ropeq(
    const float* __restrict__ qbuf, const float* __restrict__ cosb,
    const float* __restrict__ sinb, bf16* __restrict__ qpe)
{
  int gid = blockIdx.x * 256 + threadIdx.x;       // 4096*16*32
  int row = gid >> 9; int rem = gid & 511;
  int h = rem >> 5, i = rem & 31;
  int s = row & (S_TOK - 1);
  const float* p = qbuf + (long)row*3072 + h*QKD + NOPE_ + 2*i;
  float xe = p[0], xo = p[1];
  float c = cosb[s*32 + i], sn = sinb[s*32 + i];
  unsigned short* o = (unsigned short*)qpe + (long)row*1024 + h*64 + 2*i;
  ushort2 u; u.x = f2b(xe*c - xo*sn); u.y = f2b(xe*sn + xo*c);
  *(ushort2*)o = u;
}

// ---------------------------------------------------------------------------
__global__ __launch_bounds__(256) void tr64(const bf16* __restrict__ ckv,
                                            bf16* __restrict__ ckvT)
{
  const int t0 = blockIdx.x << 6, c0 = blockIdx.y << 6, b = blockIdx.z;
  const int tid = threadIdx.x;
  __shared__ unsigned short tile[64*65];
  const unsigned short* src = (const unsigned short*)ckv + (long)b*S_TOK*512;
  #pragma unroll
  for (int j = 0; j < 16; ++j) {
    int idx = tid + j*256; int r = idx >> 6, c = idx & 63;
    tile[r*65 + c] = src[(long)(t0+r)*512 + c0 + c];
  }
  __syncthreads();
  unsigned short* dst = (unsigned short*)ckvT + (long)b*512*S_TOK;
  #pragma unroll
  for (int j = 0; j < 16; ++j) {
    int idx = tid + j*256; int r = idx >> 6, t = idx & 63;
    dst[(long)(c0+r)*S_TOK + t0 + t] = tile[t*65 + r];
  }
}

// ---------------------------------------------------------------------------
__global__ __launch_bounds__(256) void wbv_cvt(const float* __restrict__ wkvb,
                                               bf16* __restrict__ wbv)
{
  int g = blockIdx.x * 256 + threadIdx.x;       // 1,048,576
  int h = g >> 16, rem = g & 65535;
  ((unsigned short*)wbv)[g] = f2b(wkvb[((long)(h*256 + NOPE_))*512 + rem]);
}

// ---------------------------------------------------------------------------
// MFMA flash attention v2 — uniform paired blocks.
// grid = 512 = (b:2, h:16, qpair:16); block processes q-tiles qt=31-qp then qt=qp
// => exactly 66 K-tiles per block; 512 blocks = 2/CU, all resident, no tail.
// kv_s blocked layout [(c-chunk c8)*32 + t]*8 halves: QK B-frag ds_read_b128
// are 2-way max (free). PV B-frags from global ckvT, batched 8-deep.
// ---------------------------------------------------------------------------
__global__ __launch_bounds__(256, 2) void attn_mfma(
    const bf16* __restrict__ qlat,   // (4096, 16*512)
    const bf16* __restrict__ qpe,    // (4096, 16*64)
    const bf16* __restrict__ ckv,    // (4096, 512)
    const bf16* __restrict__ kpe,    // (4096, 64)
    const bf16* __restrict__ ckvT,   // (B, 512, 2048)
    const bf16* __restrict__ wbv,    // (16, 128, 512)
    float* __restrict__ obuf)        // (4096, 2048)
{
  const int idx = blockIdx.x;
  const int qp = idx & 15;
  const int h  = (idx >> 4) & 15;
  const int b  = idx >> 8;
  const int tid = threadIdx.x;
  const int w = tid >> 6, lane = tid & 63;
  const int quad = lane >> 4, l16 = lane & 15;

  __shared__ __align__(16) unsigned short kv_s[72 * 32 * 8];   // 36,864 B (blocked)
  __shared__ __align__(16) unsigned short P_s[4 * 16 * 40];    //  5,120 B

  const unsigned short* ckv_b  = (const unsigned short*)ckv  + (long)b*S_TOK*512;
  const unsigned short* kpe_b  = (const unsigned short*)kpe  + (long)b*S_TOK*64;
  const unsigned short* ckvT_b = (const unsigned short*)ckvT + (long)b*512*S_TOK;
  unsigned short* Pw = P_s + w*640;

  #pragma unroll 1
  for (int half = 0; half < 2; ++half) {
    const int qt = half ? qp : (31 - qp);      // big q-tile first
    const int q0 = qt << 6;

    // ---- Q fragments: A[m=l16][k=quad*8+j], 18 K-chunks (512 lat + 64 pe)
    const long qrow = (long)b*S_TOK + q0 + w*16 + l16;
    short8 qf[18];
    {
      const unsigned short* qlp = (const unsigned short*)qlat + qrow*8192 + h*512 + quad*8;
      const unsigned short* qpp = (const unsigned short*)qpe  + qrow*1024 + h*64  + quad*8;
      #pragma unroll
      for (int kc = 0; kc < 16; ++kc) { U8 t; t.u = *(const uint4*)(qlp + kc*32); qf[kc] = t.s; }
      { U8 t; t.u = *(const uint4*)(qpp);      qf[16] = t.s; }
      { U8 t; t.u = *(const uint4*)(qpp + 32); qf[17] = t.s; }
    }

    f32x4 acc[32];
    #pragma unroll
    for (int i = 0; i < 32; ++i) acc[i] = (f32x4){0.f,0.f,0.f,0.f};
    float mi[4] = {NEG_BIG,NEG_BIG,NEG_BIG,NEG_BIG};
    float li[4] = {0.f,0.f,0.f,0.f};

    const int myqmax = q0 + w*16 + 15;
    const int ntiles = (q0 >> 5) + 2;

    for (int tile = 0; tile < ntiles; ++tile) {
      const int t0 = tile << 5;
      // ---- stage K-tile into blocked kv_s: slot = c8*32 + t ----
      #pragma unroll
      for (int j = 0; j < 8; ++j) {
        int f = tid + j*256;
        int t = f & 31, c8 = f >> 5;           // c8 in [0,64)
        *(uint4*)(kv_s + (c8*32 + t)*8) = *(const uint4*)(ckv_b + (long)(t0+t)*512 + c8*8);
      }
      { int t = tid & 31, c8p = tid >> 5;      // pe -> c8 in [64,72)
        *(uint4*)(kv_s + ((64+c8p)*32 + t)*8) = *(const uint4*)(kpe_b + (long)(t0+t)*64 + c8p*8); }
      __syncthreads();

      const bool active = (t0 <= myqmax);
      if (active) {
        // ---- scores: two 16x16 C-tiles (token halves) ----
        f32x4 sc0 = (f32x4){0.f,0.f,0.f,0.f}, sc1 = sc0;
        #pragma unroll
        for (int kc = 0; kc < 18; ++kc) {
          const int kcq = kc*4 + quad;
          U8 b0; b0.u = *(const uint4*)(kv_s + (kcq*32 + l16)*8);
          U8 b1; b1.u = *(const uint4*)(kv_s + (kcq*32 + 16 + l16)*8);
          sc0 = MFMA16x32(qf[kc], b0.s, sc0);
          sc1 = MFMA16x32(qf[kc], b1.s, sc1);
        }
        // ---- online softmax (C rows = quad*4+i, cols = l16 / 16+l16) ----
        float s0[4], s1[4], mx[4];
        #pragma unroll
        for (int i = 0; i < 4; ++i) {
          int qg = q0 + w*16 + quad*4 + i;
          s0[i] = (t0 + l16      <= qg) ? sc0[i]*SCALE_F : NEG_BIG;
          s1[i] = (t0 + 16 + l16 <= qg) ? sc1[i]*SCALE_F : NEG_BIG;
          mx[i] = fmaxf(mi[i], fmaxf(s0[i], s1[i]));
        }
        #pragma unroll
        for (int d = 1; d < 16; d <<= 1) {
          #pragma unroll
          for (int i = 0; i < 4; ++i) mx[i] = fmaxf(mx[i], __shfl_xor(mx[i], d));
        }
        float al[4], rs[4];
        #pragma unroll
        for (int i = 0; i < 4; ++i) {
          al[i] = __expf(mi[i] - mx[i]); mi[i] = mx[i];
          float p0 = __expf(s0[i] - mx[i]);
          float p1 = __expf(s1[i] - mx[i]);
          rs[i] = p0 + p1;
          Pw[(quad*4+i)*40 + l16]      = f2b(p0);
          Pw[(quad*4+i)*40 + 16 + l16] = f2b(p1);
        }
        #pragma unroll
        for (int d = 1; d < 16; d <<= 1) {
          #pragma unroll
          for (int i = 0; i < 4; ++i) rs[i] += __shfl_xor(rs[i], d);
        }
        #pragma unroll
        for (int i = 0; i < 4; ++i) li[i] = li[i]*al[i] + rs[i];
        #pragma unroll
        for (int nt = 0; nt < 32; ++nt) {
          #pragma unroll
          for (int i = 0; i < 4; ++i) acc[nt][i] *= al[i];
        }
        // ---- PV: A = P (LDS roundtrip), B = V from global ckvT, 8-deep MLP ----
        U8 ap; ap.u = *(const uint4*)(Pw + l16*40 + quad*8);
        #pragma unroll
        for (int g = 0; g < 4; ++g) {
          U8 bv[8];
          #pragma unroll
          for (int u = 0; u < 8; ++u)
            bv[u].u = *(const uint4*)(ckvT_b + (long)((g*8+u)*16 + l16)*S_TOK + t0 + quad*8);
          #pragma unroll
          for (int u = 0; u < 8; ++u)
            acc[g*8+u] = MFMA16x32(ap.s, bv[u].s, acc[g*8+u]);
        }
      }
      __syncthreads();   // kv_s reads done before next stage
    }

    // ---- epilogue: normalize, o_lat -> LDS (A layout), o = o_lat @ wb_v^T ----
    float linv[4];
    #pragma unroll
    for (int i = 0; i < 4; ++i) linv[i] = 1.0f / li[i];
    const int pass = w >> 1;
    unsigned short* ola = kv_s + (w & 1) * 16 * 520;
    #pragma unroll 1
    for (int p = 0; p < 2; ++p) {
      if (pass == p) {
        #pragma unroll
        for (int nt = 0; nt < 32; ++nt) {
          #pragma unroll
          for (int i = 0; i < 4; ++i)
            ola[(quad*4+i)*520 + nt*16 + l16] = f2b(acc[nt][i] * linv[i]);
        }
      }
      __syncthreads();
      if (pass == p) {
        f32x4 oc[8];
        #pragma unroll
        for (int nt = 0; nt < 8; ++nt) oc[nt] = (f32x4){0.f,0.f,0.f,0.f};
        #pragma unroll
        for (int kc = 0; kc < 16; ++kc) {
          U8 a; a.u = *(const uint4*)(ola + l16*520 + kc*32 + quad*8);
          #pragma unroll
          for (int nt = 0; nt < 8; ++nt) {
            U8 bw; bw.u = *(const uint4*)((const unsigned short*)wbv +
                           (long)(h*128 + nt*16 + l16)*512 + kc*32 + quad*8);
            oc[nt] = MFMA16x32(a.s, bw.s, oc[nt]);
          }
        }
        #pragma unroll
        for (int nt = 0; nt < 8; ++nt) {
          #pragma unroll
          for (int i = 0; i < 4; ++i)
            obuf[((long)b*S_TOK + q0 + w*16 + quad*4 + i)*2048 + h*128 + nt*16 + l16] = oc[nt][i];
        }
      }
      __syncthreads();
    }
  }
}

// ---------------------------------------------------------------------------
extern "C" void kernel_launch(void* const* d_in, const int* in_sizes, int n_in,
                              void* d_out, int out_size, void* d_ws, size_t ws_size,
                              hipStream_t stream)
{
  const float* x     = (const float*)d_in[0];
  const float* wq    = (const float*)d_in[1];
  const float* wkv_a = (const float*)d_in[2];
  const float* kvnw  = (const float*)d_in[3];
  const float* wkv_b = (const float*)d_in[4];
  const float* wo    = (const float*)d_in[5];
  const float* cosb  = (const float*)d_in[6];
  const float* sinb  = (const float*)d_in[7];
  float* out = (float*)d_out;

  size_t off = 0;
  char* wsb = (char*)d_ws;
  float* qbuf  = (float*)(wsb + off); off += (size_t)NROWS * 3072 * 4;   // 50.3 MB
  float* kvbuf = (float*)(wsb + off); off += (size_t)NROWS * 576  * 4;   //  9.4 MB
  bf16*  ckvb  = (bf16*) (wsb + off); off += (size_t)NROWS * 512  * 2;   //  4.2 MB
  bf16*  kpeb  = (bf16*) (wsb + off); off += (size_t)NROWS * 64   * 2;   //  0.5 MB
  bf16*  qpeb  = (bf16*) (wsb + off); off += (size_t)NROWS * 1024 * 2;   //  8.4 MB
  bf16*  qlatb = (bf16*) (wsb + off); off += (size_t)NROWS * 8192 * 2;   // 67.1 MB
  bf16*  ckvT  = (bf16*) (wsb + off); off += (size_t)NROWS * 512  * 2;   //  4.2 MB
  bf16*  wbvb  = (bf16*) (wsb + off); off += (size_t)1048576 * 2;        //  2.1 MB
  float* obuf  = (float*)(wsb + off); off += (size_t)NROWS * 2048 * 4;   // 33.6 MB

  dim3 blk(256);
  gemm_tiled<0,float><<<dim3(3072/64, NROWS/64, 1), blk, 0, stream>>>(
      x, wq, qbuf, 2048, 2048, 2048, 3072, 0, 0, 0);
  ropeq<<<dim3(8192), blk, 0, stream>>>(qbuf, cosb, sinb, qpeb);
  gemm_tiled<0,float><<<dim3(576/64, NROWS/64, 1), blk, 0, stream>>>(
      x, wkv_a, kvbuf, 2048, 2048, 2048, 576, 0, 0, 0);
  kvprep<<<dim3(NROWS), dim3(64), 0, stream>>>(kvbuf, kvnw, cosb, sinb, ckvb, kpeb);
  tr64<<<dim3(S_TOK/64, 512/64, 2), blk, 0, stream>>>(ckvb, ckvT);
  gemm_tiled<1,bf16><<<dim3(512/64, NROWS/64, NH), blk, 0, stream>>>(
      qbuf, wkv_b, qlatb, 128, 3072, 512, 8192, (long)QKD, (long)256*512, (long)512);
  wbv_cvt<<<dim3(4096), blk, 0, stream>>>(wkv_b, wbvb);
  attn_mfma<<<dim3(512), blk, 0, stream>>>(qlatb, qpeb, ckvb, kpeb, ckvT, wbvb, obuf);
  gemm_tiled<0,float><<<dim3(2048/64, NROWS/64, 1), blk, 0, stream>>>(
      obuf, wo, out, 2048, 2048, 2048, 2048, 0, 0, 0);
}

// Round 5
// 1350.987 us; speedup vs baseline: 7.1872x; 2.2963x over previous
//
#include <hip/hip_runtime.h>
#include <hip/hip_bf16.h>

typedef __hip_bfloat16 bf16;
typedef __attribute__((ext_vector_type(8))) short short8;   // 8 bf16 = 4 VGPRs (MFMA A/B frag)
typedef __attribute__((ext_vector_type(4))) float f32x4;    // MFMA C/D frag

#define S_TOK   2048
#define NROWS   4096        // B*S
#define NH      16
#define QKD     192
#define NOPE_   128
#define ROPE_   64
#define VDIM_   128
#define RANK    512
#define SCALE_F 0.07216878364870323f   // 192^-0.5
#define NEG_BIG -3.0e38f

__device__ __forceinline__ float bl(unsigned u){ union{unsigned i; float f;} t; t.i = u << 16; return t.f; }
__device__ __forceinline__ float bh(unsigned u){ union{unsigned i; float f;} t; t.i = u & 0xffff0000u; return t.f; }
__device__ __forceinline__ unsigned short f2b(float f){
  bf16 h = __float2bfloat16(f);
  return *reinterpret_cast<unsigned short*>(&h);
}
__device__ __forceinline__ void store4(bf16* p, float a, float b, float c, float d){
  ushort4 u; u.x=f2b(a); u.y=f2b(b); u.z=f2b(c); u.w=f2b(d);
  *(ushort4*)p = u;
}
union U8 { uint4 u; short8 s; };
#define MFMA16x32(a,b,c) __builtin_amdgcn_mfma_f32_16x16x32_bf16(a,b,c,0,0,0)

// ---------------------------------------------------------------------------
// cvt_bf16: f32 -> bf16 elementwise (n multiple of 1024)
// ---------------------------------------------------------------------------
__global__ __launch_bounds__(256) void cvt_bf16(const float* __restrict__ src,
                                                bf16* __restrict__ dst, int n)
{
  int g = (blockIdx.x * 256 + threadIdx.x) * 4;
  if (g < n) {
    float4 v = *(const float4*)(src + g);
    store4(dst + g, v.x, v.y, v.z, v.w);
  }
}

// ---------------------------------------------------------------------------
// tr_wbk: wkv_b K-half (h, d<128, c) f32 -> wbkT (h, c, d) bf16.  grid (2,8,16)
// ---------------------------------------------------------------------------
__global__ __launch_bounds__(256) void tr_wbk(const float* __restrict__ wkvb,
                                              bf16* __restrict__ wbkT)
{
  const int d0 = blockIdx.x << 6, c0 = blockIdx.y << 6, h = blockIdx.z;
  const int tid = threadIdx.x;
  __shared__ float tile[64*65];
  #pragma unroll
  for (int j = 0; j < 16; ++j) {
    int idx = tid + j*256; int r = idx >> 6, c = idx & 63;   // r=d, c=c
    tile[r*65 + c] = wkvb[((long)(h*256 + d0 + r))*512 + c0 + c];
  }
  __syncthreads();
  #pragma unroll
  for (int j = 0; j < 16; ++j) {
    int idx = tid + j*256; int r = idx >> 6, cc = idx & 63;  // r=c, cc=d
    ((unsigned short*)wbkT)[(long)h*65536 + (long)(c0 + r)*128 + d0 + cc] = f2b(tile[cc*65 + r]);
  }
}

// ---------------------------------------------------------------------------
// wbv_cvt: wkv_b V-half (16 x 128 x 512 f32) -> bf16 (same orientation)
// ---------------------------------------------------------------------------
__global__ __launch_bounds__(256) void wbv_cvt(const float* __restrict__ wkvb,
                                               bf16* __restrict__ wbv)
{
  int g = blockIdx.x * 256 + threadIdx.x;       // 1,048,576
  int h = g >> 16, rem = g & 65535;
  ((unsigned short*)wbv)[g] = f2b(wkvb[((long)(h*256 + NOPE_))*512 + rem]);
}

// ---------------------------------------------------------------------------
// MFMA GEMM: C[M,N] = A[M,K] @ W[N,K]^T, bf16 A/W, TOUT out.
// M,N multiples of 64; K multiple of 64. grid (N/64, M/64, Z), 256 thr.
// LDS blocked layout: slot = c8*65 + row (8 K-chunks of 8 halves x 64 rows,
// +1 row pad per chunk) -> frag ds_read_b128 are 2-way max (free).
// ---------------------------------------------------------------------------
template<typename TOUT>
__global__ __launch_bounds__(256) void gemm_mfma(
    const bf16* __restrict__ A, const bf16* __restrict__ W, TOUT* __restrict__ C,
    int K, int lda, int ldw, int ldc, long azs, long wzs, long czs)
{
  A += (long)blockIdx.z * azs;
  W += (long)blockIdx.z * wzs;
  C += (long)blockIdx.z * czs;
  __shared__ __align__(16) unsigned short As[8*65*8];   // 8320 B
  __shared__ __align__(16) unsigned short Ws[8*65*8];
  const int tid = threadIdx.x;
  const int m0 = blockIdx.y << 6, n0 = blockIdx.x << 6;
  const int w = tid >> 6, lane = tid & 63;
  const int quad = lane >> 4, l16 = lane & 15;

  const int r0 = tid >> 3, c80 = tid & 7;   // staging coords: f=tid -> (r,c8)
  const int r1 = (tid + 256) >> 3;          // second slot (same c8)

  f32x4 acc[4];
  #pragma unroll
  for (int i = 0; i < 4; ++i) acc[i] = (f32x4){0.f,0.f,0.f,0.f};

  for (int k0 = 0; k0 < K; k0 += 64) {
    uint4 a0 = *(const uint4*)(A + (long)(m0 + r0)*lda + k0 + c80*8);
    uint4 a1 = *(const uint4*)(A + (long)(m0 + r1)*lda + k0 + c80*8);
    uint4 w0 = *(const uint4*)(W + (long)(n0 + r0)*ldw + k0 + c80*8);
    uint4 w1 = *(const uint4*)(W + (long)(n0 + r1)*ldw + k0 + c80*8);
    __syncthreads();   // previous stage's reads done
    *(uint4*)(As + (c80*65 + r0)*8) = a0;
    *(uint4*)(As + (c80*65 + r1)*8) = a1;
    *(uint4*)(Ws + (c80*65 + r0)*8) = w0;
    *(uint4*)(Ws + (c80*65 + r1)*8) = w1;
    __syncthreads();
    #pragma unroll
    for (int kc = 0; kc < 2; ++kc) {
      const int kcq = kc*4 + quad;
      U8 af; af.u = *(const uint4*)(As + (kcq*65 + w*16 + l16)*8);
      #pragma unroll
      for (int nt = 0; nt < 4; ++nt) {
        U8 bf_; bf_.u = *(const uint4*)(Ws + (kcq*65 + nt*16 + l16)*8);
        acc[nt] = MFMA16x32(af.s, bf_.s, acc[nt]);
      }
    }
  }
  #pragma unroll
  for (int nt = 0; nt < 4; ++nt) {
    #pragma unroll
    for (int i = 0; i < 4; ++i) {
      long row = m0 + w*16 + quad*4 + i;
      TOUT v;
      if constexpr (sizeof(TOUT) == 2) v = __float2bfloat16(acc[nt][i]);
      else                             v = acc[nt][i];
      C[row*ldc + n0 + nt*16 + l16] = v;
    }
  }
}

// ---------------------------------------------------------------------------
// kvprep (bf16 in): RMSNorm first 512 -> ckv (bf16), RoPE last 64 -> kpe (bf16)
// ---------------------------------------------------------------------------
__global__ __launch_bounds__(64) void kvprep(
    const bf16* __restrict__ kvbuf, const float* __restrict__ wnorm,
    const float* __restrict__ cosb, const float* __restrict__ sinb,
    bf16* __restrict__ ckv, bf16* __restrict__ kpe)
{
  const int row = blockIdx.x;
  const int s = row & (S_TOK - 1);
  const int lane = threadIdx.x;
  const unsigned short* kr = (const unsigned short*)kvbuf + (long)row * 576;
  uint4 u = *(const uint4*)(kr + lane*8);
  float v[8] = { bl(u.x), bh(u.x), bl(u.y), bh(u.y), bl(u.z), bh(u.z), bl(u.w), bh(u.w) };
  float ss = 0.f;
  #pragma unroll
  for (int j = 0; j < 8; ++j) ss += v[j]*v[j];
  #pragma unroll
  for (int off = 32; off > 0; off >>= 1) ss += __shfl_down(ss, off);
  ss = __shfl(ss, 0);
  const float scl = rsqrtf(ss * (1.0f/512.0f) + 1e-6f);
  float4 w0 = *(const float4*)(wnorm + lane*8);
  float4 w1 = *(const float4*)(wnorm + lane*8 + 4);
  bf16* cd = ckv + (long)row*512 + lane*8;
  store4(cd,   v[0]*scl*w0.x, v[1]*scl*w0.y, v[2]*scl*w0.z, v[3]*scl*w0.w);
  store4(cd+4, v[4]*scl*w1.x, v[5]*scl*w1.y, v[6]*scl*w1.z, v[7]*scl*w1.w);
  if (lane < 32) {
    unsigned pe = *(const unsigned*)(kr + 512 + 2*lane);
    float xe = bl(pe), xo = bh(pe);
    float c = cosb[s*32 + lane], sn = sinb[s*32 + lane];
    ushort2 o; o.x = f2b(xe*c - xo*sn); o.y = f2b(xe*sn + xo*c);
    *(ushort2*)((unsigned short*)kpe + (long)row*64 + 2*lane) = o;
  }
}

// ---------------------------------------------------------------------------
// ropeq (bf16 in): RoPE q_pe slice of qbuf -> qpe (bf16, 4096 x 16*64)
// ---------------------------------------------------------------------------
__global__ __launch_bounds__(256) void ropeq(
    const bf16* __restrict__ qbuf, const float* __restrict__ cosb,
    const float* __restrict__ sinb, bf16* __restrict__ qpe)
{
  int gid = blockIdx.x * 256 + threadIdx.x;       // 4096*16*32
  int row = gid >> 9; int rem = gid & 511;
  int h = rem >> 5, i = rem & 31;
  int s = row & (S_TOK - 1);
  unsigned pp = *(const unsigned*)((const unsigned short*)qbuf + (long)row*3072 + h*QKD + NOPE_ + 2*i);
  float xe = bl(pp), xo = bh(pp);
  float c = cosb[s*32 + i], sn = sinb[s*32 + i];
  ushort2 u; u.x = f2b(xe*c - xo*sn); u.y = f2b(xe*sn + xo*c);
  *(ushort2*)((unsigned short*)qpe + (long)row*1024 + h*64 + 2*i) = u;
}

// ---------------------------------------------------------------------------
// tr64: ckv (b, t, c) -> ckvT (b, c, t), bf16
// ---------------------------------------------------------------------------
__global__ __launch_bounds__(256) void tr64(const bf16* __restrict__ ckv,
                                            bf16* __restrict__ ckvT)
{
  const int t0 = blockIdx.x << 6, c0 = blockIdx.y << 6, b = blockIdx.z;
  const int tid = threadIdx.x;
  __shared__ unsigned short tile[64*65];
  const unsigned short* src = (const unsigned short*)ckv + (long)b*S_TOK*512;
  #pragma unroll
  for (int j = 0; j < 16; ++j) {
    int idx = tid + j*256; int r = idx >> 6, c = idx & 63;
    tile[r*65 + c] = src[(long)(t0+r)*512 + c0 + c];
  }
  __syncthreads();
  unsigned short* dst = (unsigned short*)ckvT + (long)b*512*S_TOK;
  #pragma unroll
  for (int j = 0; j < 16; ++j) {
    int idx = tid + j*256; int r = idx >> 6, t = idx & 63;
    dst[(long)(c0+r)*S_TOK + t0 + t] = tile[t*65 + r];
  }
}

// ---------------------------------------------------------------------------
// MFMA flash attention v3 — all compute operands from LDS.
// grid = 512 = (b:2, h:16, qpair:16); block does qt=31-qp then qt=qp (66 tiles).
// kv_s: blocked [(c8*32+t)*8] for QK B-frags. kvT_s: [c*36 + t] transposed
// V-tile for PV B-frags (staged from global ckvT each tile). No per-tile
// global loads in the compute path; no register batching (no spills).
// ---------------------------------------------------------------------------
#define KVT_ST 36

__global__ __launch_bounds__(256, 2) void attn_mfma(
    const bf16* __restrict__ qlat,   // (4096, 16*512)
    const bf16* __restrict__ qpe,    // (4096, 16*64)
    const bf16* __restrict__ ckv,    // (4096, 512)
    const bf16* __restrict__ kpe,    // (4096, 64)
    const bf16* __restrict__ ckvT,   // (B, 512, 2048)
    const bf16* __restrict__ wbv,    // (16, 128, 512)
    bf16* __restrict__ obuf)         // (4096, 2048) bf16
{
  const int idx = blockIdx.x;
  const int qp = idx & 15;
  const int h  = (idx >> 4) & 15;
  const int b  = idx >> 8;
  const int tid = threadIdx.x;
  const int w = tid >> 6, lane = tid & 63;
  const int quad = lane >> 4, l16 = lane & 15;

  __shared__ __align__(16) unsigned short kv_s[72 * 32 * 8];      // 36,864 B
  __shared__ __align__(16) unsigned short kvT_s[512 * KVT_ST];    // 36,864 B
  __shared__ __align__(16) unsigned short P_s[4 * 16 * 40];       //  5,120 B

  const unsigned short* ckv_b  = (const unsigned short*)ckv  + (long)b*S_TOK*512;
  const unsigned short* kpe_b  = (const unsigned short*)kpe  + (long)b*S_TOK*64;
  const unsigned short* ckvT_b = (const unsigned short*)ckvT + (long)b*512*S_TOK;
  unsigned short* Pw = P_s + w*640;

  #pragma unroll 1
  for (int half = 0; half < 2; ++half) {
    const int qt = half ? qp : (31 - qp);      // big q-tile first
    const int q0 = qt << 6;

    // ---- Q fragments: A[m=l16][k=quad*8+j], 18 K-chunks (512 lat + 64 pe)
    const long qrow = (long)b*S_TOK + q0 + w*16 + l16;
    short8 qf[18];
    {
      const unsigned short* qlp = (const unsigned short*)qlat + qrow*8192 + h*512 + quad*8;
      const unsigned short* qpp = (const unsigned short*)qpe  + qrow*1024 + h*64  + quad*8;
      #pragma unroll
      for (int kc = 0; kc < 16; ++kc) { U8 t; t.u = *(const uint4*)(qlp + kc*32); qf[kc] = t.s; }
      { U8 t; t.u = *(const uint4*)(qpp);      qf[16] = t.s; }
      { U8 t; t.u = *(const uint4*)(qpp + 32); qf[17] = t.s; }
    }

    f32x4 acc[32];
    #pragma unroll
    for (int i = 0; i < 32; ++i) acc[i] = (f32x4){0.f,0.f,0.f,0.f};
    float mi[4] = {NEG_BIG,NEG_BIG,NEG_BIG,NEG_BIG};
    float li[4] = {0.f,0.f,0.f,0.f};

    const int myqmax = q0 + w*16 + 15;
    const int ntiles = (q0 >> 5) + 2;

    for (int tile = 0; tile < ntiles; ++tile) {
      const int t0 = tile << 5;
      // ---- stage K-tile: ckv (blocked) + kpe + transposed V-tile ----
      #pragma unroll
      for (int j = 0; j < 8; ++j) {
        int f = tid + j*256;
        int t = f & 31, c8 = f >> 5;           // c8 in [0,64)
        *(uint4*)(kv_s + (c8*32 + t)*8) = *(const uint4*)(ckv_b + (long)(t0+t)*512 + c8*8);
      }
      { int t = tid & 31, c8p = tid >> 5;      // pe -> c8 in [64,72)
        *(uint4*)(kv_s + ((64+c8p)*32 + t)*8) = *(const uint4*)(kpe_b + (long)(t0+t)*64 + c8p*8); }
      #pragma unroll
      for (int j = 0; j < 8; ++j) {
        int f = tid + j*256;                   // 2048 slots: c in [0,512), qq in [0,4)
        int c = f >> 2, qq = f & 3;
        *(uint4*)(kvT_s + c*KVT_ST + qq*8) = *(const uint4*)(ckvT_b + (long)c*S_TOK + t0 + qq*8);
      }
      __syncthreads();

      const bool active = (t0 <= myqmax);
      if (active) {
        // ---- scores: two 16x16 C-tiles (token halves) ----
        f32x4 sc0 = (f32x4){0.f,0.f,0.f,0.f}, sc1 = sc0;
        #pragma unroll
        for (int kc = 0; kc < 18; ++kc) {
          const int kcq = kc*4 + quad;
          U8 b0; b0.u = *(const uint4*)(kv_s + (kcq*32 + l16)*8);
          U8 b1; b1.u = *(const uint4*)(kv_s + (kcq*32 + 16 + l16)*8);
          sc0 = MFMA16x32(qf[kc], b0.s, sc0);
          sc1 = MFMA16x32(qf[kc], b1.s, sc1);
        }
        // ---- online softmax (C rows = quad*4+i, cols = l16 / 16+l16) ----
        float s0[4], s1[4], mx[4];
        #pragma unroll
        for (int i = 0; i < 4; ++i) {
          int qg = q0 + w*16 + quad*4 + i;
          s0[i] = (t0 + l16      <= qg) ? sc0[i]*SCALE_F : NEG_BIG;
          s1[i] = (t0 + 16 + l16 <= qg) ? sc1[i]*SCALE_F : NEG_BIG;
          mx[i] = fmaxf(mi[i], fmaxf(s0[i], s1[i]));
        }
        #pragma unroll
        for (int d = 1; d < 16; d <<= 1) {
          #pragma unroll
          for (int i = 0; i < 4; ++i) mx[i] = fmaxf(mx[i], __shfl_xor(mx[i], d));
        }
        float al[4], rs[4];
        #pragma unroll
        for (int i = 0; i < 4; ++i) {
          al[i] = __expf(mi[i] - mx[i]); mi[i] = mx[i];
          float p0 = __expf(s0[i] - mx[i]);
          float p1 = __expf(s1[i] - mx[i]);
          rs[i] = p0 + p1;
          Pw[(quad*4+i)*40 + l16]      = f2b(p0);
          Pw[(quad*4+i)*40 + 16 + l16] = f2b(p1);
        }
        #pragma unroll
        for (int d = 1; d < 16; d <<= 1) {
          #pragma unroll
          for (int i = 0; i < 4; ++i) rs[i] += __shfl_xor(rs[i], d);
        }
        #pragma unroll
        for (int i = 0; i < 4; ++i) li[i] = li[i]*al[i] + rs[i];
        #pragma unroll
        for (int nt = 0; nt < 32; ++nt) {
          #pragma unroll
          for (int i = 0; i < 4; ++i) acc[nt][i] *= al[i];
        }
        // ---- PV: A = P (LDS roundtrip), B = V^T from kvT_s ----
        U8 ap; ap.u = *(const uint4*)(Pw + l16*40 + quad*8);
        #pragma unroll
        for (int nt = 0; nt < 32; ++nt) {
          U8 bv; bv.u = *(const uint4*)(kvT_s + (nt*16 + l16)*KVT_ST + quad*8);
          acc[nt] = MFMA16x32(ap.s, bv.s, acc[nt]);
        }
      }
      __syncthreads();   // kv_s/kvT_s reads done before next stage
    }

    // ---- epilogue: normalize, o_lat -> LDS (A layout), o = o_lat @ wb_v^T ----
    float linv[4];
    #pragma unroll
    for (int i = 0; i < 4; ++i) linv[i] = 1.0f / li[i];
    const int pass = w >> 1;
    unsigned short* ola = kv_s + (w & 1) * 16 * 520;
    #pragma unroll 1
    for (int p = 0; p < 2; ++p) {
      if (pass == p) {
        #pragma unroll
        for (int nt = 0; nt < 32; ++nt) {
          #pragma unroll
          for (int i = 0; i < 4; ++i)
            ola[(quad*4+i)*520 + nt*16 + l16] = f2b(acc[nt][i] * linv[i]);
        }
      }
      __syncthreads();
      if (pass == p) {
        f32x4 oc[8];
        #pragma unroll
        for (int nt = 0; nt < 8; ++nt) oc[nt] = (f32x4){0.f,0.f,0.f,0.f};
        #pragma unroll
        for (int kc = 0; kc < 16; ++kc) {
          U8 a; a.u = *(const uint4*)(ola + l16*520 + kc*32 + quad*8);
          #pragma unroll
          for (int nt = 0; nt < 8; ++nt) {
            U8 bw; bw.u = *(const uint4*)((const unsigned short*)wbv +
                           (long)(h*128 + nt*16 + l16)*512 + kc*32 + quad*8);
            oc[nt] = MFMA16x32(a.s, bw.s, oc[nt]);
          }
        }
        #pragma unroll
        for (int nt = 0; nt < 8; ++nt) {
          #pragma unroll
          for (int i = 0; i < 4; ++i)
            ((unsigned short*)obuf)[((long)b*S_TOK + q0 + w*16 + quad*4 + i)*2048
                                    + h*128 + nt*16 + l16] = f2b(oc[nt][i]);
        }
      }
      __syncthreads();
    }
  }
}

// ---------------------------------------------------------------------------
extern "C" void kernel_launch(void* const* d_in, const int* in_sizes, int n_in,
                              void* d_out, int out_size, void* d_ws, size_t ws_size,
                              hipStream_t stream)
{
  const float* x     = (const float*)d_in[0];
  const float* wq    = (const float*)d_in[1];
  const float* wkv_a = (const float*)d_in[2];
  const float* kvnw  = (const float*)d_in[3];
  const float* wkv_b = (const float*)d_in[4];
  const float* wo    = (const float*)d_in[5];
  const float* cosb  = (const float*)d_in[6];
  const float* sinb  = (const float*)d_in[7];
  float* out = (float*)d_out;

  size_t off = 0;
  char* wsb = (char*)d_ws;
  bf16* xb    = (bf16*)(wsb + off); off += (size_t)NROWS * 2048 * 2;   // 16.8 MB
  bf16* wqb   = (bf16*)(wsb + off); off += (size_t)3072 * 2048 * 2;    // 12.6 MB
  bf16* wab   = (bf16*)(wsb + off); off += (size_t)576  * 2048 * 2;    //  2.4 MB
  bf16* wob   = (bf16*)(wsb + off); off += (size_t)2048 * 2048 * 2;    //  8.4 MB
  bf16* wbkT  = (bf16*)(wsb + off); off += (size_t)NH * 512 * 128 * 2; //  2.1 MB
  bf16* wbvb  = (bf16*)(wsb + off); off += (size_t)1048576 * 2;        //  2.1 MB
  bf16* qbuf  = (bf16*)(wsb + off); off += (size_t)NROWS * 3072 * 2;   // 25.2 MB
  bf16* kvbuf = (bf16*)(wsb + off); off += (size_t)NROWS * 576  * 2;   //  4.7 MB
  bf16* ckvb  = (bf16*)(wsb + off); off += (size_t)NROWS * 512  * 2;   //  4.2 MB
  bf16* kpeb  = (bf16*)(wsb + off); off += (size_t)NROWS * 64   * 2;   //  0.5 MB
  bf16* qpeb  = (bf16*)(wsb + off); off += (size_t)NROWS * 1024 * 2;   //  8.4 MB
  bf16* qlatb = (bf16*)(wsb + off); off += (size_t)NROWS * 8192 * 2;   // 67.1 MB
  bf16* ckvT  = (bf16*)(wsb + off); off += (size_t)NROWS * 512  * 2;   //  4.2 MB
  bf16* obuf  = (bf16*)(wsb + off); off += (size_t)NROWS * 2048 * 2;   // 16.8 MB

  dim3 blk(256);
  // input/weight conversions
  cvt_bf16<<<dim3(8388608/1024),  blk, 0, stream>>>(x,     xb,  8388608);
  cvt_bf16<<<dim3(6291456/1024),  blk, 0, stream>>>(wq,    wqb, 6291456);
  cvt_bf16<<<dim3(1179648/1024),  blk, 0, stream>>>(wkv_a, wab, 1179648);
  cvt_bf16<<<dim3(4194304/1024),  blk, 0, stream>>>(wo,    wob, 4194304);
  tr_wbk<<<dim3(2, 8, NH), blk, 0, stream>>>(wkv_b, wbkT);
  wbv_cvt<<<dim3(4096), blk, 0, stream>>>(wkv_b, wbvb);
  // q = x @ wq^T
  gemm_mfma<bf16><<<dim3(3072/64, NROWS/64, 1), blk, 0, stream>>>(
      xb, wqb, qbuf, 2048, 2048, 2048, 3072, 0, 0, 0);
  ropeq<<<dim3(8192), blk, 0, stream>>>(qbuf, cosb, sinb, qpeb);
  // kv = x @ wkv_a^T
  gemm_mfma<bf16><<<dim3(576/64, NROWS/64, 1), blk, 0, stream>>>(
      xb, wab, kvbuf, 2048, 2048, 2048, 576, 0, 0, 0);
  kvprep<<<dim3(NROWS), dim3(64), 0, stream>>>(kvbuf, kvnw, cosb, sinb, ckvb, kpeb);
  tr64<<<dim3(S_TOK/64, 512/64, 2), blk, 0, stream>>>(ckvb, ckvT);
  // q_lat[h] = q_nope[:,h] @ wbkT[h]^T   (wbkT rows are c, cols d -> mode-0)
  gemm_mfma<bf16><<<dim3(512/64, NROWS/64, NH), blk, 0, stream>>>(
      qbuf, wbkT, qlatb, 128, 3072, 128, 8192,
      (long)QKD, (long)512*128, (long)512);
  // MFMA flash attention (+ fused o_lat @ wb_v^T)
  attn_mfma<<<dim3(512), blk, 0, stream>>>(qlatb, qpeb, ckvb, kpeb, ckvT, wbvb, obuf);
  // out = o @ wo^T (f32 out)
  gemm_mfma<float><<<dim3(2048/64, NROWS/64, 1), blk, 0, stream>>>(
      obuf, wob, out, 2048, 2048, 2048, 2048, 0, 0, 0);
}